// Round 8
// baseline (621.072 us; speedup 1.0000x reference)
//
#include <hip/hip_runtime.h>
#include <cstdint>
#include <cstddef>

// ---------- types / helpers ----------
typedef float  v4f  __attribute__((ext_vector_type(4)));
typedef __bf16 v8bf __attribute__((ext_vector_type(8)));
typedef __bf16 v4bf __attribute__((ext_vector_type(4)));

__device__ __forceinline__ float b2f(unsigned short u) {
  union { unsigned int i; float f; } cv; cv.i = ((unsigned int)u) << 16; return cv.f;
}
__device__ __forceinline__ unsigned short f2b(float f) {
  union { float f; unsigned int i; } cv; cv.f = f;
  unsigned int i = cv.i;
  i += 0x7fffu + ((i >> 16) & 1u);      // round-to-nearest-even
  return (unsigned short)(i >> 16);
}
__device__ __forceinline__ unsigned short f2b_trunc(float f) {
  union { float f; unsigned int i; } cv; cv.f = f;
  return (unsigned short)(cv.i >> 16);  // truncate (cheap); used for P only
}
__device__ __forceinline__ float gelu_exact(float x) {
  return 0.5f * x * (1.0f + erff(x * 0.70710678118654752f));
}
__device__ __forceinline__ void g2l16(const unsigned short* g, unsigned short* l) {
  __builtin_amdgcn_global_load_lds(
      (const __attribute__((address_space(1))) void*)g,
      (__attribute__((address_space(3))) void*)l,
      16, 0, 0);
}

// ---------- transpose + fp32->bf16 convert: in[R,C] f32 -> out[C,R] bf16 ----------
__global__ __launch_bounds__(256) void transpose_k(const float* __restrict__ in,
                                                   unsigned short* __restrict__ out,
                                                   int R, int C) {
  __shared__ float tile[32][33];
  const int tx = threadIdx.x, ty = threadIdx.y;
  const int r0 = blockIdx.y * 32, c0 = blockIdx.x * 32;
#pragma unroll
  for (int j = 0; j < 4; ++j)
    tile[ty + 8 * j][tx] = in[(size_t)(r0 + ty + 8 * j) * C + c0 + tx];
  __syncthreads();
#pragma unroll
  for (int j = 0; j < 4; ++j)
    out[(size_t)(c0 + ty + 8 * j) * R + r0 + tx] = f2b(tile[tx][ty + 8 * j]);
}

// ---------- layernorm over DIM=1024 (fp32 in, bf16 out), one block per row ----------
__global__ __launch_bounds__(256) void ln_kernel(const float* __restrict__ x,
                                                 const float* __restrict__ g,
                                                 const float* __restrict__ bta,
                                                 unsigned short* __restrict__ out) {
  const int r = blockIdx.x, t = threadIdx.x;
  const float4 raw = *(const float4*)(x + (size_t)r * 1024 + t * 4);
  float v0 = raw.x, v1 = raw.y, v2 = raw.z, v3 = raw.w;
  float s  = v0 + v1 + v2 + v3;
  float s2 = v0 * v0 + v1 * v1 + v2 * v2 + v3 * v3;
#pragma unroll
  for (int off = 32; off > 0; off >>= 1) {
    s  += __shfl_down(s, off);
    s2 += __shfl_down(s2, off);
  }
  __shared__ float red[8];
  const int w = t >> 6, lane = t & 63;
  if (lane == 0) { red[w] = s; red[4 + w] = s2; }
  __syncthreads();
  if (t == 0) {
    float ts = red[0] + red[1] + red[2] + red[3];
    float t2 = red[4] + red[5] + red[6] + red[7];
    float mu = ts * (1.0f / 1024.0f);
    float var = t2 * (1.0f / 1024.0f) - mu * mu;
    red[0] = mu;
    red[1] = rsqrtf(var + 1e-5f);
  }
  __syncthreads();
  const float mu = red[0], rs = red[1];
  const float4 graw = *(const float4*)(g + t * 4);
  const float4 braw = *(const float4*)(bta + t * 4);
  ushort4 o;
  o.x = f2b((v0 - mu) * rs * graw.x + braw.x);
  o.y = f2b((v1 - mu) * rs * graw.y + braw.y);
  o.z = f2b((v2 - mu) * rs * graw.z + braw.z);
  o.w = f2b((v3 - mu) * rs * graw.w + braw.w);
  *(ushort4*)(out + (size_t)r * 1024 + t * 4) = o;
}

// ---------- MFMA GEMM: C[M,N] = A[M,K] @ Bt[N,K]^T (+bias)(+gelu)(+res) ----------
__global__ __launch_bounds__(256, 2) void gemm_bt(const unsigned short* __restrict__ A,
                                                  const unsigned short* __restrict__ Bt,
                                                  const float* __restrict__ bias,
                                                  const float* __restrict__ res,
                                                  void* __restrict__ Cout,
                                                  int M, int N, int K, int act, int out_bf16) {
  __shared__ __align__(16) unsigned short As[128 * 32];
  __shared__ __align__(16) unsigned short Bs[128 * 32];
  const int t = threadIdx.x;
  const int lane = t & 63, w = t >> 6;
  const int wr = (w >> 1) * 64, wc = (w & 1) * 64;
  const int lr = lane & 15, lq = lane >> 4;
  const int m0 = blockIdx.y * 128, n0 = blockIdx.x * 128;

  v4f acc[4][4];
#pragma unroll
  for (int mi = 0; mi < 4; ++mi)
#pragma unroll
    for (int ni = 0; ni < 4; ++ni)
      acc[mi][ni] = (v4f){0.f, 0.f, 0.f, 0.f};

  for (int k0 = 0; k0 < K; k0 += 32) {
#pragma unroll
    for (int j = 0; j < 2; ++j) {
      const int c = t + j * 256;
      const int row = c >> 2, off = (c & 3) << 3;
      g2l16(A  + (size_t)(m0 + row) * K + k0 + off, As + c * 8);
      g2l16(Bt + (size_t)(n0 + row) * K + k0 + off, Bs + c * 8);
    }
    __syncthreads();
    v8bf af[4], bfr[4];
#pragma unroll
    for (int i = 0; i < 4; ++i) {
      af[i]  = *(const v8bf*)(As + (wr + i * 16 + lr) * 32 + lq * 8);
      bfr[i] = *(const v8bf*)(Bs + (wc + i * 16 + lr) * 32 + lq * 8);
    }
#pragma unroll
    for (int mi = 0; mi < 4; ++mi)
#pragma unroll
      for (int ni = 0; ni < 4; ++ni)
        acc[mi][ni] = __builtin_amdgcn_mfma_f32_16x16x32_bf16(af[mi], bfr[ni], acc[mi][ni], 0, 0, 0);
    __syncthreads();
  }

#pragma unroll
  for (int mi = 0; mi < 4; ++mi) {
#pragma unroll
    for (int ni = 0; ni < 4; ++ni) {
      const int col = n0 + wc + ni * 16 + lr;
      const float bv = bias ? bias[col] : 0.0f;
#pragma unroll
      for (int r = 0; r < 4; ++r) {
        const int row = m0 + wr + mi * 16 + lq * 4 + r;
        float v = acc[mi][ni][r] + bv;
        if (act) v = gelu_exact(v);
        if (res) v += res[(size_t)row * N + col];
        if (out_bf16)
          ((unsigned short*)Cout)[(size_t)row * N + col] = f2b(v);
        else
          ((float*)Cout)[(size_t)row * N + col] = v;
      }
    }
  }
}

// ---------- V restage: qkv[token][3072] v-part -> Vt[(b*16+h)*64+d][2048 tokens] ----------
__global__ __launch_bounds__(256) void vt_k(const unsigned short* __restrict__ qkv,
                                            unsigned short* __restrict__ Vt) {
  const int t = threadIdx.x;
  const int n = blockIdx.x * 256 + t, h = blockIdx.y, b = blockIdx.z;
  const size_t src = (size_t)(b * 2048 + n) * 3072 + 2048 + h * 64;
  unsigned short v[64];
#pragma unroll
  for (int j = 0; j < 8; ++j)
    *(uint4*)(v + j * 8) = *(const uint4*)(qkv + src + j * 8);
  const size_t dstbase = ((size_t)(b * 16 + h) * 64) * 2048 + n;
#pragma unroll
  for (int d = 0; d < 64; ++d)
    Vt[dstbase + (size_t)d * 2048] = v[d];
}

// ---------- MFMA flash attention ----------
// LDS strides: Ks/Vs rows 80 elems (160 B: frag-read conflicts 8->4-way, 16B-aligned
// staging preserved); Ps rows 76 elems (152 B: scalar P-writes 4->2-way = free; reads
// as 2x b64). P uses truncating bf16 cvt; lsum accumulates the ROUNDED p so
// numerator/denominator stay consistent (bias cancels in the softmax divide).
__global__ __launch_bounds__(256, 2) void attn_mfma(const unsigned short* __restrict__ qkv,
                                                    const unsigned short* __restrict__ Vt,
                                                    unsigned short* __restrict__ out) {
  __shared__ __align__(16) unsigned short Ks[64 * 80];      // 10.0 KB
  __shared__ __align__(16) unsigned short Vs[64 * 80];      // 10.0 KB
  __shared__ __align__(16) unsigned short Ps[4][32 * 76];   // 19.0 KB
  const int t = threadIdx.x;
  const int lane = t & 63, w = t >> 6;
  const int lr = lane & 15, lq = lane >> 4;
  const int h = blockIdx.y, b = blockIdx.z;
  const int q0 = blockIdx.x * 128 + w * 32;

  v8bf aq[2][2];
#pragma unroll
  for (int mi = 0; mi < 2; ++mi)
#pragma unroll
    for (int kq = 0; kq < 2; ++kq)
      aq[mi][kq] = *(const v8bf*)(qkv + (size_t)(b * 2048 + q0 + mi * 16 + lr) * 3072
                                  + h * 64 + kq * 32 + lq * 8);

  v4f acc_o[2][4];
  float lsum[2][4];
#pragma unroll
  for (int mi = 0; mi < 2; ++mi)
#pragma unroll
    for (int di = 0; di < 4; ++di)
      acc_o[mi][di] = (v4f){0.f, 0.f, 0.f, 0.f};
#pragma unroll
  for (int mi = 0; mi < 2; ++mi)
#pragma unroll
    for (int r = 0; r < 4; ++r)
      lsum[mi][r] = 0.0f;

  for (int kt = 0; kt < 32; ++kt) {
    const int kt0 = kt * 64;
#pragma unroll
    for (int j = 0; j < 2; ++j) {
      const int c = t + j * 256;
      const int row = c >> 3, off = (c & 7) * 8;
      *(uint4*)(Ks + row * 80 + off) =
          *(const uint4*)(qkv + (size_t)(b * 2048 + kt0 + row) * 3072 + 1024 + h * 64 + off);
      *(uint4*)(Vs + row * 80 + off) =
          *(const uint4*)(Vt + ((size_t)(b * 16 + h) * 64 + row) * 2048 + kt0 + off);
    }
    __syncthreads();

    v4f s_acc[2][4];
#pragma unroll
    for (int mi = 0; mi < 2; ++mi)
#pragma unroll
      for (int ni = 0; ni < 4; ++ni)
        s_acc[mi][ni] = (v4f){0.f, 0.f, 0.f, 0.f};
#pragma unroll
    for (int kq = 0; kq < 2; ++kq) {
      v8bf bk[4];
#pragma unroll
      for (int ni = 0; ni < 4; ++ni)
        bk[ni] = *(const v8bf*)(Ks + (ni * 16 + lr) * 80 + kq * 32 + lq * 8);
#pragma unroll
      for (int mi = 0; mi < 2; ++mi)
#pragma unroll
        for (int ni = 0; ni < 4; ++ni)
          s_acc[mi][ni] = __builtin_amdgcn_mfma_f32_16x16x32_bf16(aq[mi][kq], bk[ni], s_acc[mi][ni], 0, 0, 0);
    }

#pragma unroll
    for (int mi = 0; mi < 2; ++mi)
#pragma unroll
      for (int ni = 0; ni < 4; ++ni)
#pragma unroll
        for (int r = 0; r < 4; ++r) {
          const float p = __expf(s_acc[mi][ni][r] * 0.125f);
          const unsigned short pb = f2b_trunc(p);
          lsum[mi][r] += b2f(pb);
          Ps[w][(mi * 16 + lq * 4 + r) * 76 + ni * 16 + lr] = pb;
        }

#pragma unroll
    for (int ks = 0; ks < 2; ++ks) {
      v8bf ap[2], bv[4];
#pragma unroll
      for (int mi = 0; mi < 2; ++mi) {
        const unsigned short* base = Ps[w] + (mi * 16 + lr) * 76 + ks * 32 + lq * 8;
        const v4bf lo = *(const v4bf*)(base);
        const v4bf hi = *(const v4bf*)(base + 4);
        ap[mi] = __builtin_shufflevector(lo, hi, 0, 1, 2, 3, 4, 5, 6, 7);
      }
#pragma unroll
      for (int di = 0; di < 4; ++di)
        bv[di] = *(const v8bf*)(Vs + (di * 16 + lr) * 80 + ks * 32 + lq * 8);
#pragma unroll
      for (int mi = 0; mi < 2; ++mi)
#pragma unroll
        for (int di = 0; di < 4; ++di)
          acc_o[mi][di] = __builtin_amdgcn_mfma_f32_16x16x32_bf16(ap[mi], bv[di], acc_o[mi][di], 0, 0, 0);
    }
    __syncthreads();
  }

#pragma unroll
  for (int mi = 0; mi < 2; ++mi)
#pragma unroll
    for (int r = 0; r < 4; ++r) {
      float v = lsum[mi][r];
      v += __shfl_xor(v, 1);
      v += __shfl_xor(v, 2);
      v += __shfl_xor(v, 4);
      v += __shfl_xor(v, 8);
      lsum[mi][r] = 1.0f / v;
    }

#pragma unroll
  for (int mi = 0; mi < 2; ++mi)
#pragma unroll
    for (int di = 0; di < 4; ++di)
#pragma unroll
      for (int r = 0; r < 4; ++r)
        out[(size_t)(b * 2048 + q0 + mi * 16 + lq * 4 + r) * 1024 + h * 64 + di * 16 + lr] =
            f2b(acc_o[mi][di][r] * lsum[mi][r]);
}

// ---------- launch ----------
extern "C" void kernel_launch(void* const* d_in, const int* in_sizes, int n_in,
                              void* d_out, int out_size, void* d_ws, size_t ws_size,
                              hipStream_t stream) {
  (void)in_sizes; (void)n_in; (void)out_size; (void)ws_size;
  const float* x      = (const float*)d_in[0];
  const float* w_qkv  = (const float*)d_in[1];
  const float* w_proj = (const float*)d_in[2];
  const float* b_proj = (const float*)d_in[3];
  const float* ln1_g  = (const float*)d_in[4];
  const float* ln1_b  = (const float*)d_in[5];
  const float* w1     = (const float*)d_in[6];
  const float* b1     = (const float*)d_in[7];
  const float* w2     = (const float*)d_in[8];
  const float* b2     = (const float*)d_in[9];
  const float* ln2_g  = (const float*)d_in[10];
  const float* ln2_b  = (const float*)d_in[11];
  float* out = (float*)d_out;

  char* ws = (char*)d_ws;
  unsigned short* T_a   = (unsigned short*)(ws);
  unsigned short* T_b   = (unsigned short*)(ws + 8388608);
  float*          x2buf = (float*)         (ws + 16777216);
  unsigned short* Vtbuf = (unsigned short*)(ws + 16777216);   // borrows x2 region pre-proj
  unsigned short* Hbuf  = (unsigned short*)(ws + 50331648);
  unsigned short* qkvb  = (unsigned short*)(ws + 67108864);
  unsigned short* h3buf = (unsigned short*)(ws + 50331648);
  unsigned short* h2buf = (unsigned short*)d_out;

  const dim3 tb(32, 8);
  transpose_k<<<dim3(96, 32),  tb, 0, stream>>>(w_qkv,  T_a, 1024, 3072);
  transpose_k<<<dim3(32, 32),  tb, 0, stream>>>(w_proj, T_b, 1024, 1024);
  ln_kernel<<<8192, 256, 0, stream>>>(x, ln1_g, ln1_b, Hbuf);
  gemm_bt<<<dim3(24, 64), 256, 0, stream>>>(Hbuf, T_a, nullptr, nullptr, qkvb, 8192, 3072, 1024, 0, 1);
  transpose_k<<<dim3(128, 32), tb, 0, stream>>>(w1, T_a, 1024, 4096);
  vt_k<<<dim3(8, 16, 4), 256, 0, stream>>>(qkvb, Vtbuf);
  attn_mfma<<<dim3(16, 16, 4), 256, 0, stream>>>(qkvb, Vtbuf, Hbuf);
  gemm_bt<<<dim3(8, 64), 256, 0, stream>>>(Hbuf, T_b, b_proj, x, x2buf, 8192, 1024, 1024, 0, 0);
  transpose_k<<<dim3(32, 128), tb, 0, stream>>>(w2, T_b, 4096, 1024);
  ln_kernel<<<8192, 256, 0, stream>>>(x2buf, ln2_g, ln2_b, h2buf);
  gemm_bt<<<dim3(32, 64), 256, 0, stream>>>(h2buf, T_a, b1, nullptr, h3buf, 8192, 4096, 1024, 1, 1);
  gemm_bt<<<dim3(8, 64), 256, 0, stream>>>(h3buf, T_b, b2, x2buf, out, 8192, 1024, 4096, 0, 0);
}

// Round 9
// 608.397 us; speedup vs baseline: 1.0208x; 1.0208x over previous
//
#include <hip/hip_runtime.h>
#include <cstdint>
#include <cstddef>

// ---------- types / helpers ----------
typedef float  v4f  __attribute__((ext_vector_type(4)));
typedef __bf16 v8bf __attribute__((ext_vector_type(8)));
typedef __bf16 v4bf __attribute__((ext_vector_type(4)));

__device__ __forceinline__ float b2f(unsigned short u) {
  union { unsigned int i; float f; } cv; cv.i = ((unsigned int)u) << 16; return cv.f;
}
__device__ __forceinline__ unsigned short f2b(float f) {
  union { float f; unsigned int i; } cv; cv.f = f;
  unsigned int i = cv.i;
  i += 0x7fffu + ((i >> 16) & 1u);      // round-to-nearest-even
  return (unsigned short)(i >> 16);
}
__device__ __forceinline__ unsigned short f2b_trunc(float f) {
  union { float f; unsigned int i; } cv; cv.f = f;
  return (unsigned short)(cv.i >> 16);  // truncate (cheap); P only
}
__device__ __forceinline__ float gelu_exact(float x) {
  return 0.5f * x * (1.0f + erff(x * 0.70710678118654752f));
}
__device__ __forceinline__ void g2l16(const unsigned short* g, unsigned short* l) {
  __builtin_amdgcn_global_load_lds(
      (const __attribute__((address_space(1))) void*)g,
      (__attribute__((address_space(3))) void*)l,
      16, 0, 0);
}

// ---------- transpose + fp32->bf16 convert: in[R,C] f32 -> out[C,R] bf16 ----------
__global__ __launch_bounds__(256) void transpose_k(const float* __restrict__ in,
                                                   unsigned short* __restrict__ out,
                                                   int R, int C) {
  __shared__ float tile[32][33];
  const int tx = threadIdx.x, ty = threadIdx.y;
  const int r0 = blockIdx.y * 32, c0 = blockIdx.x * 32;
#pragma unroll
  for (int j = 0; j < 4; ++j)
    tile[ty + 8 * j][tx] = in[(size_t)(r0 + ty + 8 * j) * C + c0 + tx];
  __syncthreads();
#pragma unroll
  for (int j = 0; j < 4; ++j)
    out[(size_t)(c0 + ty + 8 * j) * R + r0 + tx] = f2b(tile[tx][ty + 8 * j]);
}

// ---------- layernorm over DIM=1024 (fp32 or bf16 in, bf16 out) ----------
__global__ __launch_bounds__(256) void ln_kernel(const void* __restrict__ xp, int in_bf16,
                                                 const float* __restrict__ g,
                                                 const float* __restrict__ bta,
                                                 unsigned short* __restrict__ out) {
  const int r = blockIdx.x, t = threadIdx.x;
  float v0, v1, v2, v3;
  if (in_bf16) {
    const ushort4 raw = *(const ushort4*)((const unsigned short*)xp + (size_t)r * 1024 + t * 4);
    v0 = b2f(raw.x); v1 = b2f(raw.y); v2 = b2f(raw.z); v3 = b2f(raw.w);
  } else {
    const float4 raw = *(const float4*)((const float*)xp + (size_t)r * 1024 + t * 4);
    v0 = raw.x; v1 = raw.y; v2 = raw.z; v3 = raw.w;
  }
  float s  = v0 + v1 + v2 + v3;
  float s2 = v0 * v0 + v1 * v1 + v2 * v2 + v3 * v3;
#pragma unroll
  for (int off = 32; off > 0; off >>= 1) {
    s  += __shfl_down(s, off);
    s2 += __shfl_down(s2, off);
  }
  __shared__ float red[8];
  const int w = t >> 6, lane = t & 63;
  if (lane == 0) { red[w] = s; red[4 + w] = s2; }
  __syncthreads();
  if (t == 0) {
    float ts = red[0] + red[1] + red[2] + red[3];
    float t2 = red[4] + red[5] + red[6] + red[7];
    float mu = ts * (1.0f / 1024.0f);
    float var = t2 * (1.0f / 1024.0f) - mu * mu;
    red[0] = mu;
    red[1] = rsqrtf(var + 1e-5f);
  }
  __syncthreads();
  const float mu = red[0], rs = red[1];
  const float4 graw = *(const float4*)(g + t * 4);
  const float4 braw = *(const float4*)(bta + t * 4);
  ushort4 o;
  o.x = f2b((v0 - mu) * rs * graw.x + braw.x);
  o.y = f2b((v1 - mu) * rs * graw.y + braw.y);
  o.z = f2b((v2 - mu) * rs * graw.z + braw.z);
  o.w = f2b((v3 - mu) * rs * graw.w + braw.w);
  *(ushort4*)(out + (size_t)r * 1024 + t * 4) = o;
}

// ---------- MFMA GEMM: C[M,N] = A[M,K] @ Bt[N,K]^T (+bias)(+gelu)(+res) ----------
// swap_xy=1: blockIdx.x indexes M-tiles, blockIdx.y N-tiles => linear bid = col*gridX+row,
// XCD = row%8: all column-blocks of one row-tile co-locate on one XCD (A-tile L2-resident).
__global__ __launch_bounds__(256, 2) void gemm_bt(const unsigned short* __restrict__ A,
                                                  const unsigned short* __restrict__ Bt,
                                                  const float* __restrict__ bias,
                                                  const void* __restrict__ res, int res_bf16,
                                                  void* __restrict__ Cout,
                                                  int M, int N, int K, int act, int out_bf16,
                                                  int swap_xy) {
  __shared__ __align__(16) unsigned short As[128 * 32];
  __shared__ __align__(16) unsigned short Bs[128 * 32];
  const int t = threadIdx.x;
  const int lane = t & 63, w = t >> 6;
  const int wr = (w >> 1) * 64, wc = (w & 1) * 64;
  const int lr = lane & 15, lq = lane >> 4;
  const int mb = swap_xy ? blockIdx.x : blockIdx.y;
  const int nb = swap_xy ? blockIdx.y : blockIdx.x;
  const int m0 = mb * 128, n0 = nb * 128;

  v4f acc[4][4];
#pragma unroll
  for (int mi = 0; mi < 4; ++mi)
#pragma unroll
    for (int ni = 0; ni < 4; ++ni)
      acc[mi][ni] = (v4f){0.f, 0.f, 0.f, 0.f};

  for (int k0 = 0; k0 < K; k0 += 32) {
#pragma unroll
    for (int j = 0; j < 2; ++j) {
      const int c = t + j * 256;
      const int row = c >> 2, off = (c & 3) << 3;
      g2l16(A  + (size_t)(m0 + row) * K + k0 + off, As + c * 8);
      g2l16(Bt + (size_t)(n0 + row) * K + k0 + off, Bs + c * 8);
    }
    __syncthreads();
    v8bf af[4], bfr[4];
#pragma unroll
    for (int i = 0; i < 4; ++i) {
      af[i]  = *(const v8bf*)(As + (wr + i * 16 + lr) * 32 + lq * 8);
      bfr[i] = *(const v8bf*)(Bs + (wc + i * 16 + lr) * 32 + lq * 8);
    }
#pragma unroll
    for (int mi = 0; mi < 4; ++mi)
#pragma unroll
      for (int ni = 0; ni < 4; ++ni)
        acc[mi][ni] = __builtin_amdgcn_mfma_f32_16x16x32_bf16(af[mi], bfr[ni], acc[mi][ni], 0, 0, 0);
    __syncthreads();
  }

#pragma unroll
  for (int mi = 0; mi < 4; ++mi) {
#pragma unroll
    for (int ni = 0; ni < 4; ++ni) {
      const int col = n0 + wc + ni * 16 + lr;
      const float bv = bias ? bias[col] : 0.0f;
#pragma unroll
      for (int r = 0; r < 4; ++r) {
        const int row = m0 + wr + mi * 16 + lq * 4 + r;
        float v = acc[mi][ni][r] + bv;
        if (act) v = gelu_exact(v);
        if (res) {
          v += res_bf16 ? b2f(((const unsigned short*)res)[(size_t)row * N + col])
                        : ((const float*)res)[(size_t)row * N + col];
        }
        if (out_bf16)
          ((unsigned short*)Cout)[(size_t)row * N + col] = f2b(v);
        else
          ((float*)Cout)[(size_t)row * N + col] = v;
      }
    }
  }
}

// ---------- V restage: qkv[token][3072] v-part -> Vt[(b*16+h)*64+d][2048 tokens] ----------
__global__ __launch_bounds__(256) void vt_k(const unsigned short* __restrict__ qkv,
                                            unsigned short* __restrict__ Vt) {
  const int t = threadIdx.x;
  const int n = blockIdx.x * 256 + t, h = blockIdx.y, b = blockIdx.z;
  const size_t src = (size_t)(b * 2048 + n) * 3072 + 2048 + h * 64;
  unsigned short v[64];
#pragma unroll
  for (int j = 0; j < 8; ++j)
    *(uint4*)(v + j * 8) = *(const uint4*)(qkv + src + j * 8);
  const size_t dstbase = ((size_t)(b * 16 + h) * 64) * 2048 + n;
#pragma unroll
  for (int d = 0; d < 64; ++d)
    Vt[dstbase + (size_t)d * 2048] = v[d];
}

// ---------- MFMA flash attention ----------
// blockIdx.x = head, blockIdx.y = q-tile: bid%8 = h%8 => all q-tiles of one (b,h)
// land on one XCD, keeping its K/V (512 KB) L2-resident.
__global__ __launch_bounds__(256, 2) void attn_mfma(const unsigned short* __restrict__ qkv,
                                                    const unsigned short* __restrict__ Vt,
                                                    unsigned short* __restrict__ out) {
  __shared__ __align__(16) unsigned short Ks[64 * 80];
  __shared__ __align__(16) unsigned short Vs[64 * 80];
  __shared__ __align__(16) unsigned short Ps[4][32 * 76];
  const int t = threadIdx.x;
  const int lane = t & 63, w = t >> 6;
  const int lr = lane & 15, lq = lane >> 4;
  const int h = blockIdx.x, b = blockIdx.z;
  const int q0 = blockIdx.y * 128 + w * 32;

  v8bf aq[2][2];
#pragma unroll
  for (int mi = 0; mi < 2; ++mi)
#pragma unroll
    for (int kq = 0; kq < 2; ++kq)
      aq[mi][kq] = *(const v8bf*)(qkv + (size_t)(b * 2048 + q0 + mi * 16 + lr) * 3072
                                  + h * 64 + kq * 32 + lq * 8);

  v4f acc_o[2][4];
  float lsum[2][4];
#pragma unroll
  for (int mi = 0; mi < 2; ++mi)
#pragma unroll
    for (int di = 0; di < 4; ++di)
      acc_o[mi][di] = (v4f){0.f, 0.f, 0.f, 0.f};
#pragma unroll
  for (int mi = 0; mi < 2; ++mi)
#pragma unroll
    for (int r = 0; r < 4; ++r)
      lsum[mi][r] = 0.0f;

  for (int kt = 0; kt < 32; ++kt) {
    const int kt0 = kt * 64;
#pragma unroll
    for (int j = 0; j < 2; ++j) {
      const int c = t + j * 256;
      const int row = c >> 3, off = (c & 7) * 8;
      *(uint4*)(Ks + row * 80 + off) =
          *(const uint4*)(qkv + (size_t)(b * 2048 + kt0 + row) * 3072 + 1024 + h * 64 + off);
      *(uint4*)(Vs + row * 80 + off) =
          *(const uint4*)(Vt + ((size_t)(b * 16 + h) * 64 + row) * 2048 + kt0 + off);
    }
    __syncthreads();

    v4f s_acc[2][4];
#pragma unroll
    for (int mi = 0; mi < 2; ++mi)
#pragma unroll
      for (int ni = 0; ni < 4; ++ni)
        s_acc[mi][ni] = (v4f){0.f, 0.f, 0.f, 0.f};
#pragma unroll
    for (int kq = 0; kq < 2; ++kq) {
      v8bf bk[4];
#pragma unroll
      for (int ni = 0; ni < 4; ++ni)
        bk[ni] = *(const v8bf*)(Ks + (ni * 16 + lr) * 80 + kq * 32 + lq * 8);
#pragma unroll
      for (int mi = 0; mi < 2; ++mi)
#pragma unroll
        for (int ni = 0; ni < 4; ++ni)
          s_acc[mi][ni] = __builtin_amdgcn_mfma_f32_16x16x32_bf16(aq[mi][kq], bk[ni], s_acc[mi][ni], 0, 0, 0);
    }

#pragma unroll
    for (int mi = 0; mi < 2; ++mi)
#pragma unroll
      for (int ni = 0; ni < 4; ++ni)
#pragma unroll
        for (int r = 0; r < 4; ++r) {
          const float p = __expf(s_acc[mi][ni][r] * 0.125f);
          const unsigned short pb = f2b_trunc(p);
          lsum[mi][r] += b2f(pb);
          Ps[w][(mi * 16 + lq * 4 + r) * 76 + ni * 16 + lr] = pb;
        }

#pragma unroll
    for (int ks = 0; ks < 2; ++ks) {
      v8bf ap[2], bv[4];
#pragma unroll
      for (int mi = 0; mi < 2; ++mi) {
        const unsigned short* base = Ps[w] + (mi * 16 + lr) * 76 + ks * 32 + lq * 8;
        const v4bf lo = *(const v4bf*)(base);
        const v4bf hi = *(const v4bf*)(base + 4);
        ap[mi] = __builtin_shufflevector(lo, hi, 0, 1, 2, 3, 4, 5, 6, 7);
      }
#pragma unroll
      for (int di = 0; di < 4; ++di)
        bv[di] = *(const v8bf*)(Vs + (di * 16 + lr) * 80 + ks * 32 + lq * 8);
#pragma unroll
      for (int mi = 0; mi < 2; ++mi)
#pragma unroll
        for (int di = 0; di < 4; ++di)
          acc_o[mi][di] = __builtin_amdgcn_mfma_f32_16x16x32_bf16(ap[mi], bv[di], acc_o[mi][di], 0, 0, 0);
    }
    __syncthreads();
  }

#pragma unroll
  for (int mi = 0; mi < 2; ++mi)
#pragma unroll
    for (int r = 0; r < 4; ++r) {
      float v = lsum[mi][r];
      v += __shfl_xor(v, 1);
      v += __shfl_xor(v, 2);
      v += __shfl_xor(v, 4);
      v += __shfl_xor(v, 8);
      lsum[mi][r] = 1.0f / v;
    }

#pragma unroll
  for (int mi = 0; mi < 2; ++mi)
#pragma unroll
    for (int di = 0; di < 4; ++di)
#pragma unroll
      for (int r = 0; r < 4; ++r)
        out[(size_t)(b * 2048 + q0 + mi * 16 + lq * 4 + r) * 1024 + h * 64 + di * 16 + lr] =
            f2b(acc_o[mi][di][r] * lsum[mi][r]);
}

// ---------- launch ----------
// ws layout (112 MiB): T_a [0,8M) wt_qkv->wt_w1; T_b [8,16M) wt_proj->wt_w2;
// x2 bf16 [16,32M); Vt [32,48M); H [48,64M) h->o; qkv [64,112M);
// h3 [48,112M) overlays dead H+qkv; h2 bf16 in d_out scratch.
extern "C" void kernel_launch(void* const* d_in, const int* in_sizes, int n_in,
                              void* d_out, int out_size, void* d_ws, size_t ws_size,
                              hipStream_t stream) {
  (void)in_sizes; (void)n_in; (void)out_size; (void)ws_size;
  const float* x      = (const float*)d_in[0];
  const float* w_qkv  = (const float*)d_in[1];
  const float* w_proj = (const float*)d_in[2];
  const float* b_proj = (const float*)d_in[3];
  const float* ln1_g  = (const float*)d_in[4];
  const float* ln1_b  = (const float*)d_in[5];
  const float* w1     = (const float*)d_in[6];
  const float* b1     = (const float*)d_in[7];
  const float* w2     = (const float*)d_in[8];
  const float* b2     = (const float*)d_in[9];
  const float* ln2_g  = (const float*)d_in[10];
  const float* ln2_b  = (const float*)d_in[11];
  float* out = (float*)d_out;

  char* ws = (char*)d_ws;
  unsigned short* T_a   = (unsigned short*)(ws);
  unsigned short* T_b   = (unsigned short*)(ws + 8388608);
  unsigned short* x2buf = (unsigned short*)(ws + 16777216);   // bf16 [8192,1024]
  unsigned short* Vtbuf = (unsigned short*)(ws + 33554432);
  unsigned short* Hbuf  = (unsigned short*)(ws + 50331648);
  unsigned short* qkvb  = (unsigned short*)(ws + 67108864);
  unsigned short* h3buf = (unsigned short*)(ws + 50331648);
  unsigned short* h2buf = (unsigned short*)d_out;

  const dim3 tb(32, 8);
  transpose_k<<<dim3(96, 32),  tb, 0, stream>>>(w_qkv,  T_a, 1024, 3072);
  transpose_k<<<dim3(32, 32),  tb, 0, stream>>>(w_proj, T_b, 1024, 1024);
  // h = LN1(x)
  ln_kernel<<<8192, 256, 0, stream>>>(x, 0, ln1_g, ln1_b, Hbuf);
  // qkv = h @ w_qkv
  gemm_bt<<<dim3(24, 64), 256, 0, stream>>>(Hbuf, T_a, nullptr, nullptr, 0, qkvb, 8192, 3072, 1024, 0, 1, 0);
  transpose_k<<<dim3(128, 32), tb, 0, stream>>>(w1, T_a, 1024, 4096);
  // attention
  vt_k<<<dim3(8, 16, 4), 256, 0, stream>>>(qkvb, Vtbuf);
  attn_mfma<<<dim3(16, 16, 4), 256, 0, stream>>>(qkvb, Vtbuf, Hbuf);
  // x2 = o @ w_proj + b_proj + x  (bf16 out, XCD row-sharing swizzle)
  gemm_bt<<<dim3(64, 8), 256, 0, stream>>>(Hbuf, T_b, b_proj, x, 0, x2buf, 8192, 1024, 1024, 0, 1, 1);
  transpose_k<<<dim3(32, 128), tb, 0, stream>>>(w2, T_b, 4096, 1024);
  // h2 = LN2(x2)
  ln_kernel<<<8192, 256, 0, stream>>>(x2buf, 1, ln2_g, ln2_b, h2buf);
  // h3 = gelu(h2 @ w1 + b1)
  gemm_bt<<<dim3(32, 64), 256, 0, stream>>>(h2buf, T_a, b1, nullptr, 0, h3buf, 8192, 4096, 1024, 1, 1, 0);
  // out = h3 @ w2 + b2 + x2  (fp32 out, swizzle)
  gemm_bt<<<dim3(64, 8), 256, 0, stream>>>(h3buf, T_b, b2, x2buf, 1, out, 8192, 1024, 4096, 0, 0, 1);
}